// Round 6
// baseline (13780.060 us; speedup 1.0000x reference)
//
#include <hip/hip_runtime.h>
#include <hip/hip_bf16.h>
#include <stdint.h>

// ---------------------------------------------------------------------------
// CustomSimpleGRU R5 = R3 + L1 K-coverage fix.
//   R2/R3 failed DETERMINISTICALLY (identical absmax 0.1204 with and without
//   fences) -> math bug, not coherence. Found: L1's two K-halves are 1024
//   elements = 32 MFMA k-steps each, but L1I ran only 16 iters/half -> half
//   of every L1 gate sum was missing (FLOP audit: 268M vs 537M MACs/step).
//   Fix: 32 iters/half, waitvm<(i<24?7:31-i)>, prefetch while i+8<32.
//
//   Design (unchanged otherwise):
//   - 192 WGs x 256 thr, 128KB LDS -> 1 WG/CU, all resident.
//   - L0: WGs 0..63 (cg): M=128 (4 waves x 32 rows), N=32 (16 z + 16 n cols
//     j in [cg*16,cg*16+16)), K=1152. L1: WGs 64..191 (cg,g): M=64 (4 waves
//     x 16 rows), N=32, K=2048 (h0(t) | h1(t-1)). Weights bf16 in LDS.
//   - Full-K per wave (no reduction barriers), h fp32 in regs, bf16 h rings
//     (4 slots) in ws via LLC (sc0 sc1), flags[rowblock][64 colgroups].
//   - Producer: stores, fence(RELEASE,"agent"), flag=t+1. Consumers poll
//     lane-parallel (64 flags/load + __all).
//   - L1 does h1(t-1) half first (overlaps L0's h0(t) production).
// ---------------------------------------------------------------------------

#define SEQLEN 512

typedef short bhalf8 __attribute__((ext_vector_type(8)));
typedef float f32x4  __attribute__((ext_vector_type(4)));

#define OFF_F0   0
#define OFF_F1   2048
#define OFF_H0   8192
#define OFF_H1   (OFF_H0 + 4*262144)
#define OFF_H1F  (OFF_H1 + 4*262144)
#define WS_END   (OFF_H1F + 524288)
#define LDS_BYTES 131072

__device__ __forceinline__ unsigned int bfbits(float f) {
  __hip_bfloat16 h = __float2bfloat16(f);
  unsigned short u; __builtin_memcpy(&u, &h, 2);
  return (unsigned int)u;
}
template<int N> __device__ __forceinline__ void waitvm() {
  asm volatile("s_waitcnt vmcnt(%0)" :: "n"(N));
}
#define GLOADA(dst, p)  asm volatile("global_load_dwordx4 %0, %1, off sc0 sc1" : "=v"(dst) : "v"((unsigned long long)(p)) : "memory")
#define STORE_BF16(p,u) asm volatile("global_store_short %0, %1, off sc0 sc1" :: "v"((unsigned long long)(p)), "v"(u) : "memory")
#define STORE_F32(p,f)  asm volatile("global_store_dword %0, %1, off sc0 sc1" :: "v"((unsigned long long)(p)), "v"(f) : "memory")
#define RELEASE_FENCE() __builtin_amdgcn_fence(__ATOMIC_RELEASE, "agent")

#define MFMA(a,b,c) __builtin_amdgcn_mfma_f32_16x16x32_bf16((a),(b),(c),0,0,0)

// ---- L0 h-part: 32 k-iters (k=128..1151), 2 loads/iter, depth-4-iter pipe
#define L0I(i) { \
  waitvm<((i) < 28 ? 6 : 2*(31-(i)))>(); \
  asm volatile("" : "+v"(af[(i)&3][0]), "+v"(af[(i)&3][1])); \
  { const int kb = 256 + (i)*64 + l4*16; \
    bhalf8 bvz = *(const bhalf8*)(smem + l15*2304 + (kb ^ swz)); \
    bhalf8 bvn = *(const bhalf8*)(smem + (16+l15)*2304 + (kb ^ swz)); \
    acc[0][0] = MFMA(af[(i)&3][0], bvz, acc[0][0]); \
    acc[0][1] = MFMA(af[(i)&3][0], bvn, acc[0][1]); \
    acc[1][0] = MFMA(af[(i)&3][1], bvz, acc[1][0]); \
    acc[1][1] = MFMA(af[(i)&3][1], bvn, acc[1][1]); } \
  if ((i)+4 < 32) { GLOADA(af[(i)&3][0], ab0 + ((i)+4)*32); \
                    GLOADA(af[(i)&3][1], ab1 + ((i)+4)*32); } \
}

// ---- L1 half: 32 k-iters (1024 elements), 1 load/iter, depth-8 pipeline
#define L1I(i, KOFF, abx) { \
  waitvm<((i) < 24 ? 7 : (31-(i)))>(); \
  asm volatile("" : "+v"(af[(i)&7])); \
  { const int kb = (KOFF) + (i)*64 + l4*16; \
    bhalf8 bvz = *(const bhalf8*)(smem + l15*4096 + (kb ^ swz)); \
    bhalf8 bvn = *(const bhalf8*)(smem + (16+l15)*4096 + (kb ^ swz)); \
    accz = MFMA(af[(i)&7], bvz, accz); \
    accn = MFMA(af[(i)&7], bvn, accn); } \
  if ((i)+8 < 32) { GLOADA(af[(i)&7], (abx) + ((i)+8)*32); } \
}

#define L1HALF(KOFF, abx) \
  L1I(0,KOFF,abx)  L1I(1,KOFF,abx)  L1I(2,KOFF,abx)  L1I(3,KOFF,abx)  \
  L1I(4,KOFF,abx)  L1I(5,KOFF,abx)  L1I(6,KOFF,abx)  L1I(7,KOFF,abx)  \
  L1I(8,KOFF,abx)  L1I(9,KOFF,abx)  L1I(10,KOFF,abx) L1I(11,KOFF,abx) \
  L1I(12,KOFF,abx) L1I(13,KOFF,abx) L1I(14,KOFF,abx) L1I(15,KOFF,abx) \
  L1I(16,KOFF,abx) L1I(17,KOFF,abx) L1I(18,KOFF,abx) L1I(19,KOFF,abx) \
  L1I(20,KOFF,abx) L1I(21,KOFF,abx) L1I(22,KOFF,abx) L1I(23,KOFF,abx) \
  L1I(24,KOFF,abx) L1I(25,KOFF,abx) L1I(26,KOFF,abx) L1I(27,KOFF,abx) \
  L1I(28,KOFF,abx) L1I(29,KOFF,abx) L1I(30,KOFF,abx) L1I(31,KOFF,abx)

__global__ __launch_bounds__(256,1) void gru_persist(
    const float* __restrict__ x,  const float* __restrict__ W0,
    const float* __restrict__ b0, const float* __restrict__ W1,
    const float* __restrict__ b1, char* __restrict__ ws)
{
  extern __shared__ char smem[];
  const int tid = threadIdx.x, lane = tid & 63, wv = tid >> 6;
  const int l4 = lane >> 4, l15 = lane & 15;
  const int swz = (l15 & 7) << 4;
  const int wg = blockIdx.x;
  const bool isL0 = wg < 64;

  int* flags0 = (int*)(ws + OFF_F0);
  int* flags1 = (int*)(ws + OFF_F1);
  unsigned short* h0b = (unsigned short*)(ws + OFF_H0);
  unsigned short* h1b = (unsigned short*)(ws + OFF_H1);
  float*          h1f = (float*)(ws + OFF_H1F);

  int cg, g = 0;
  if (isL0) cg = wg;
  else { cg = (wg - 64) >> 1; g = (wg - 64) & 1; }

  // ---- one-time: stage (z,n) weight columns into LDS, bf16 [n][k], swizzled
  {
    const int n = tid & 31, kg = tid >> 5;
    const int col = (n < 16) ? cg*16 + n : 2048 + cg*16 + (n - 16);
    if (isL0) {
      for (int it = 0; it < 144; ++it) {
        const int k = kg*144 + it;
        *(unsigned short*)(smem + n*2304 + ((2*k) ^ ((n&7)<<4))) =
            (unsigned short)bfbits(W0[(size_t)k*3072 + col]);
      }
    } else {
      for (int it = 0; it < 256; ++it) {
        const int k = kg*256 + it;
        *(unsigned short*)(smem + n*4096 + ((2*k) ^ ((n&7)<<4))) =
            (unsigned short)bfbits(W1[(size_t)k*3072 + col]);
      }
    }
  }
  __syncthreads();

  float bz, bn;
  if (isL0) { bz = b0[cg*16 + l15]; bn = b0[2048 + cg*16 + l15]; }
  else      { bz = b1[cg*16 + l15]; bn = b1[2048 + cg*16 + l15]; }

  if (isL0) {
    // ================= LAYER 0 =================
    const int rb0 = 2*wv, rb1 = 2*wv + 1;
    float hp[2][4] = {{0.f,0.f,0.f,0.f},{0.f,0.f,0.f,0.f}};
    const int* f0a = flags0 + rb0*64 + lane;
    const int* f0b = flags0 + rb1*64 + lane;
    const int* f1a = flags1 + rb0*64 + lane;
    const int* f1b = flags1 + rb1*64 + lane;

    #pragma unroll 1
    for (int t = 0; t < SEQLEN; ++t) {
      f32x4 acc[2][2];
      #pragma unroll
      for (int mt = 0; mt < 2; ++mt)
        #pragma unroll
        for (int r = 0; r < 4; ++r) { acc[mt][0][r] = bz; acc[mt][1][r] = bn; }

      // ---- x-part (always ready): K = 0..127
      #pragma unroll
      for (int mt = 0; mt < 2; ++mt) {
        const int b = wv*32 + mt*16 + l15;
        const float* xp = x + ((size_t)b*SEQLEN + t)*128 + l4*8;
        #pragma unroll
        for (int kk = 0; kk < 4; ++kk) {
          f32x4 lo = *(const f32x4*)(xp + kk*32);
          f32x4 hi = *(const f32x4*)(xp + kk*32 + 4);
          bhalf8 ax;
          #pragma unroll
          for (int e = 0; e < 4; ++e) {
            ax[e]   = (short)bfbits(lo[e]);
            ax[4+e] = (short)bfbits(hi[e]);
          }
          const int kb = kk*64 + l4*16;
          bhalf8 bvz = *(const bhalf8*)(smem + l15*2304 + (kb ^ swz));
          bhalf8 bvn = *(const bhalf8*)(smem + (16+l15)*2304 + (kb ^ swz));
          acc[mt][0] = MFMA(ax, bvz, acc[mt][0]);
          acc[mt][1] = MFMA(ax, bvn, acc[mt][1]);
        }
      }

      // ---- poll: h0(t-1) ready (data), L1 consumed h0(t-4) (WAR)
      {
        const int tgt0 = t, tgt1 = t - 3;
        for (;;) {
          int a  = __hip_atomic_load(f0a, __ATOMIC_RELAXED, __HIP_MEMORY_SCOPE_AGENT);
          int b2 = __hip_atomic_load(f0b, __ATOMIC_RELAXED, __HIP_MEMORY_SCOPE_AGENT);
          int c  = __hip_atomic_load(f1a, __ATOMIC_RELAXED, __HIP_MEMORY_SCOPE_AGENT);
          int d  = __hip_atomic_load(f1b, __ATOMIC_RELAXED, __HIP_MEMORY_SCOPE_AGENT);
          if (__all((a >= tgt0) && (b2 >= tgt0) && (c >= tgt1) && (d >= tgt1))) break;
          __builtin_amdgcn_s_sleep(1);
        }
      }

      // ---- h-part: K = 128..1151 from h0(t-1), slot (t+3)&3
      {
        const unsigned short* src = h0b + (size_t)((t+3)&3)*131072;
        const unsigned short* ab0 = src + (size_t)(wv*32 +      l15)*1024 + l4*8;
        const unsigned short* ab1 = src + (size_t)(wv*32 + 16 + l15)*1024 + l4*8;
        bhalf8 af[4][2];
        GLOADA(af[0][0], ab0+ 0); GLOADA(af[0][1], ab1+ 0);
        GLOADA(af[1][0], ab0+32); GLOADA(af[1][1], ab1+32);
        GLOADA(af[2][0], ab0+64); GLOADA(af[2][1], ab1+64);
        GLOADA(af[3][0], ab0+96); GLOADA(af[3][1], ab1+96);
        L0I(0)  L0I(1)  L0I(2)  L0I(3)  L0I(4)  L0I(5)  L0I(6)  L0I(7)
        L0I(8)  L0I(9)  L0I(10) L0I(11) L0I(12) L0I(13) L0I(14) L0I(15)
        L0I(16) L0I(17) L0I(18) L0I(19) L0I(20) L0I(21) L0I(22) L0I(23)
        L0I(24) L0I(25) L0I(26) L0I(27) L0I(28) L0I(29) L0I(30) L0I(31)
      }

      // ---- eltwise + store h0(t) (slot t&3) + release fence + post flags
      {
        unsigned short* h0out = h0b + (size_t)(t&3)*131072;
        #pragma unroll
        for (int mt = 0; mt < 2; ++mt)
          #pragma unroll
          for (int r = 0; r < 4; ++r) {
            const float z  = 1.0f/(1.0f + __expf(-acc[mt][0][r]));
            const float e2 = __expf(2.0f*acc[mt][1][r]);
            const float n  = (e2 - 1.0f)/(e2 + 1.0f);
            const float hn = n + z*(hp[mt][r] - n);
            hp[mt][r] = hn;
            const int row = wv*32 + mt*16 + l4*4 + r;
            STORE_BF16(h0out + (size_t)row*1024 + cg*16 + l15, bfbits(hn));
          }
        RELEASE_FENCE();   // data LLC-visible before flag post
        if (lane == 0) {
          __hip_atomic_store(flags0 + rb0*64 + cg, t+1, __ATOMIC_RELAXED, __HIP_MEMORY_SCOPE_AGENT);
          __hip_atomic_store(flags0 + rb1*64 + cg, t+1, __ATOMIC_RELAXED, __HIP_MEMORY_SCOPE_AGENT);
        }
      }
    }
  } else {
    // ================= LAYER 1 =================
    const int rb = g*4 + wv;
    const int rowbase = g*64 + wv*16;
    float hp[4] = {0.f,0.f,0.f,0.f};
    const int* f1p = flags1 + rb*64 + lane;
    const int* f0p = flags0 + rb*64 + lane;

    #pragma unroll 1
    for (int t = 0; t < SEQLEN; ++t) {
      f32x4 accz, accn;
      #pragma unroll
      for (int r = 0; r < 4; ++r) { accz[r] = bz; accn[r] = bn; }

      // ---- poll: h1(t-1) ready (also covers own-ring WAR)
      for (;;) {
        int a = __hip_atomic_load(f1p, __ATOMIC_RELAXED, __HIP_MEMORY_SCOPE_AGENT);
        if (__all(a >= t)) break;
        __builtin_amdgcn_s_sleep(1);
      }

      // ---- h1(t-1) K-half (W1 rows 1024..2047), slot (t+3)&3
      {
        const unsigned short* src1 = h1b + (size_t)((t+3)&3)*131072;
        const unsigned short* ab = src1 + (size_t)(rowbase + l15)*1024 + l4*8;
        bhalf8 af[8];
        GLOADA(af[0], ab+  0); GLOADA(af[1], ab+ 32);
        GLOADA(af[2], ab+ 64); GLOADA(af[3], ab+ 96);
        GLOADA(af[4], ab+128); GLOADA(af[5], ab+160);
        GLOADA(af[6], ab+192); GLOADA(af[7], ab+224);
        L1HALF(2048, ab)
      }

      // ---- poll: h0(t) ready
      for (;;) {
        int a = __hip_atomic_load(f0p, __ATOMIC_RELAXED, __HIP_MEMORY_SCOPE_AGENT);
        if (__all(a >= t+1)) break;
        __builtin_amdgcn_s_sleep(1);
      }

      // ---- h0(t) K-half (W1 rows 0..1023), slot t&3
      {
        const unsigned short* src0 = h0b + (size_t)(t&3)*131072;
        const unsigned short* ab2 = src0 + (size_t)(rowbase + l15)*1024 + l4*8;
        bhalf8 af[8];
        GLOADA(af[0], ab2+  0); GLOADA(af[1], ab2+ 32);
        GLOADA(af[2], ab2+ 64); GLOADA(af[3], ab2+ 96);
        GLOADA(af[4], ab2+128); GLOADA(af[5], ab2+160);
        GLOADA(af[6], ab2+192); GLOADA(af[7], ab2+224);
        L1HALF(0, ab2)
      }

      // ---- eltwise + store h1(t) + release fence + post
      {
        unsigned short* h1out = h1b + (size_t)(t&3)*131072;
        #pragma unroll
        for (int r = 0; r < 4; ++r) {
          const float z  = 1.0f/(1.0f + __expf(-accz[r]));
          const float e2 = __expf(2.0f*accn[r]);
          const float n  = (e2 - 1.0f)/(e2 + 1.0f);
          const float hn = n + z*(hp[r] - n);
          hp[r] = hn;
          const int row = rowbase + l4*4 + r;
          STORE_BF16(h1out + (size_t)row*1024 + cg*16 + l15, bfbits(hn));
          if (t == SEQLEN-1)
            STORE_F32(h1f + (size_t)row*1024 + cg*16 + l15, hn);
        }
        RELEASE_FENCE();   // data LLC-visible before flag post
        if (lane == 0)
          __hip_atomic_store(flags1 + rb*64 + cg, t+1, __ATOMIC_RELAXED, __HIP_MEMORY_SCOPE_AGENT);
      }
    }
  }
}

__global__ void gru_pred(const char* __restrict__ ws, const float* __restrict__ Wfc,
                         const float* __restrict__ bfc, float* __restrict__ out)
{
  const int b = blockIdx.x;
  const int l = threadIdx.x;   // 64 threads = 1 wave per batch row
  const float* h = (const float*)(ws + OFF_H1F) + (size_t)b*1024;
  float s = 0.0f;
  for (int k = l; k < 1024; k += 64) s += h[k] * Wfc[k];
  #pragma unroll
  for (int off = 32; off > 0; off >>= 1) s += __shfl_down(s, off);
  if (l == 0) out[b] = s + bfc[0];
}

extern "C" void kernel_launch(void* const* d_in, const int* in_sizes, int n_in,
                              void* d_out, int out_size, void* d_ws, size_t ws_size,
                              hipStream_t stream)
{
  (void)in_sizes; (void)n_in; (void)out_size; (void)ws_size;
  const float* x   = (const float*)d_in[0];
  const float* W0  = (const float*)d_in[1];
  const float* b0  = (const float*)d_in[2];
  const float* W1  = (const float*)d_in[3];
  const float* b1  = (const float*)d_in[4];
  const float* Wfc = (const float*)d_in[5];
  const float* bfc = (const float*)d_in[6];
  char* ws = (char*)d_ws;

  hipFuncSetAttribute(reinterpret_cast<const void*>(gru_persist),
                      hipFuncAttributeMaxDynamicSharedMemorySize, LDS_BYTES);
  hipMemsetAsync(ws, 0, WS_END, stream);   // flags + h ring slots = 0
  hipLaunchKernelGGL(gru_persist, dim3(192), dim3(256), LDS_BYTES, stream,
                     x, W0, b0, W1, b1, ws);
  hipLaunchKernelGGL(gru_pred, dim3(128), dim3(64), 0, stream,
                     ws, Wfc, bfc, (float*)d_out);
}